// Round 5
// baseline (221.588 us; speedup 1.0000x reference)
//
#include <hip/hip_runtime.h>
#include <hip/hip_bf16.h>

#define NPIX 4096
#define CCH  256
#define HID  64
#define BAT  4
#define XSTR 264    // proj LDS row stride (halfs)
#define PTS  136    // attn P-tile row stride (halfs)
#define RTHR 8.0f   // online-softmax defer-rescale threshold (exp2 units)

// Fragment-order tensor layout (round-11):
//   All MFMA operand tensors (Qf, Kf, Vt, Wg) are stored as 16x32 fragment
//   tiles of 512 halfs (1 KB); a wave's fragment load is base + lane*8 halfs
//   -> ONE contiguous 1KB segment per instruction.
//
// Round-16 (this round): EXACT v13 attn structure (verified 97.6us; round-4's
//   3-change bundle added pure stall and was reverted), with ONE change:
//   n-split 2x -> grid 1024, 32 columns per block. Rationale: v13 is
//   latency-bound at 2 waves/SIMD (grid-limited, occupancy 20%); the split
//   halves per-wave register state (qf/Sacc/Oacc/Li/Mv) so VGPR drops
//   ~124 -> ~100 < 128, letting 4 blocks/CU = 4 waves/SIMD co-reside
//   naturally (no forced launch_bounds cap -> no spill risk). Per-XCD L2
//   read volume doubles to ~4 TB/s, just under the ~4.3 TB/s ceiling.

using f32x4 = __attribute__((ext_vector_type(4))) float;
using h16x8 = __attribute__((ext_vector_type(8))) _Float16;
using u16x4 = __attribute__((ext_vector_type(4))) unsigned short;

#define L2E 1.44269504088896340736f

__device__ __forceinline__ unsigned short f2h(float f) {
    _Float16 h = (_Float16)f;
    return __builtin_bit_cast(unsigned short, h);
}
__device__ __forceinline__ h16x8 ldg_fragh(const unsigned short* p) {
    uint4 v = *reinterpret_cast<const uint4*>(p);
    return __builtin_bit_cast(h16x8, v);
}
__device__ __forceinline__ h16x8 lds_fragh(const unsigned short* p) {
    return *reinterpret_cast<const h16x8*>(p);
}
__device__ __forceinline__ unsigned int pk2h(float a, float b) {
    auto t = __builtin_amdgcn_cvt_pkrtz(a, b);   // <2 x half>, RTZ
    return __builtin_bit_cast(unsigned int, t);
}
__device__ __forceinline__ float sel4(float a0, float a1, float a2, float a3, int q) {
    float x = (q & 1) ? a1 : a0;
    float y = (q & 1) ? a3 : a2;
    return (q & 2) ? y : x;
}

// ---------------------------------------------------------------------------
// W conversion -> frag-order Wg [384 rows][256 k] fp16: 24 row-tiles x 8
// k-tiles = 192 tiles x 512 halfs. Rows 0-63 Wq (x log2e), 64-127 Wk, rest Wv.
// ---------------------------------------------------------------------------
__global__ __launch_bounds__(256, 1) void wcvt_kernel(
    const float* __restrict__ Wq, const float* __restrict__ Wk,
    const float* __restrict__ Wv, unsigned short* __restrict__ Wg)
{
    int tid = blockIdx.x * 256 + threadIdx.x;       // 0..12287
    int tile = tid >> 6, lane = tid & 63;
    int r = (tile >> 3) * 16 + (lane & 15);
    int c = (tile & 7) * 32 + (lane >> 4) * 8;
    const float* src; float sc;
    if (r < 64)       { src = Wq + r * CCH + c;        sc = L2E; }
    else if (r < 128) { src = Wk + (r - 64) * CCH + c; sc = 1.0f; }
    else              { src = Wv + (r - 128) * CCH + c; sc = 1.0f; }
    float4 a = *reinterpret_cast<const float4*>(src);
    float4 b4 = *reinterpret_cast<const float4*>(src + 4);
    uint4 out;
    out.x = pk2h(a.x * sc, a.y * sc);
    out.y = pk2h(a.z * sc, a.w * sc);
    out.z = pk2h(b4.x * sc, b4.y * sc);
    out.w = pk2h(b4.z * sc, b4.w * sc);
    *reinterpret_cast<uint4*>(Wg + tile * 512 + lane * 8) = out;
}

// ---------------------------------------------------------------------------
// fp16 MFMA projection v11: frag-order W loads (contiguous 1KB/wave) and
// frag-order Q/K/V stores (one 8B store/lane, contiguous 512B/wave).
// ---------------------------------------------------------------------------
__global__ __launch_bounds__(256, 2) void proj_kernel(
    const float* __restrict__ x1, const float* __restrict__ x2,
    const unsigned short* __restrict__ Wg,
    const float* __restrict__ bq, const float* __restrict__ bk,
    const float* __restrict__ bv,
    unsigned short* __restrict__ Qf, unsigned short* __restrict__ Kf,
    unsigned short* __restrict__ Vt)
{
    __shared__ unsigned short xs[32][XSTR];

    const int Lb = blockIdx.x;
    const int sb = Lb & 7;              // XCD-locality swizzle
    const int tile = Lb >> 3;
    const int s = sb >> 2, b = sb & 3;
    const float* x = s ? x2 : x1;
    const int n0 = tile * 32;
    const int t = threadIdx.x;
    const int lane = t & 63;
    const int w = __builtin_amdgcn_readfirstlane(t >> 6);
    const int quad = lane >> 4, lq = lane & 15;

    // stage x^T fp16 into LDS
    {
        const int n = t & 31;
        const int g = t >> 5;
        const float* xb = x + (size_t)(b * CCH) * NPIX + n0;
        #pragma unroll
        for (int i = 0; i < 8; ++i) {
            int c0 = g * 4 + i * 32;
            u16x4 hv;
            #pragma unroll
            for (int j = 0; j < 4; ++j)
                hv[j] = f2h(xb[(size_t)(c0 + j) * NPIX + n]);
            *reinterpret_cast<u16x4*>(&xs[n][c0]) = hv;
        }
    }
    __syncthreads();

    // hoist x fragments (both ntiles, full K=256)
    h16x8 xf[2][8];
    #pragma unroll
    for (int nt = 0; nt < 2; ++nt)
        #pragma unroll
        for (int ks = 0; ks < 8; ++ks)
            xf[nt][ks] = lds_fragh(&xs[nt * 16 + lq][ks * 32 + quad * 8]);

    unsigned short* Qb = Qf + (size_t)(s * BAT + b) * (NPIX * HID);
    unsigned short* Kb = Kf + (size_t)(s * BAT + b) * (NPIX * HID);
    unsigned short* Vb = Vt + (size_t)(s * BAT + b) * ((size_t)CCH * NPIX);

    // W fragment double-buffer, frag-order contiguous loads
    h16x8 wf[2][8];
    {
        const unsigned short* wp = Wg + (size_t)(w * 6 * 8) * 512 + lane * 8;
        #pragma unroll
        for (int ks = 0; ks < 8; ++ks) wf[0][ks] = ldg_fragh(wp + ks * 512);
    }

    #pragma unroll
    for (int hloop = 0; hloop < 6; ++hloop) {
        const int cur = hloop & 1;
        const int idx = w * 6 + hloop;                  // wave-uniform, 0..23
        const int kind = idx < 4 ? 0 : (idx < 8 ? 1 : 2);

        if (hloop < 5) {
            const unsigned short* wp = Wg + (size_t)((idx + 1) * 8) * 512 + lane * 8;
            #pragma unroll
            for (int ks = 0; ks < 8; ++ks) wf[cur ^ 1][ks] = ldg_fragh(wp + ks * 512);
        }

        if (kind == 2) {
            // V: D[n][c] = mfma(xf, wf): m = n0+nt*16+quad*4+reg, c = cbase+lq
            const int cbase = (idx - 8) * 16;
            const float bbv = bv[cbase + lq];
            #pragma unroll
            for (int nt = 0; nt < 2; ++nt) {
                f32x4 acc = (f32x4){0.f, 0.f, 0.f, 0.f};
                #pragma unroll
                for (int ks = 0; ks < 8; ++ks)
                    acc = __builtin_amdgcn_mfma_f32_16x16x32_f16(xf[nt][ks], wf[cur][ks], acc, 0, 0, 0);
                u16x4 pk;
                #pragma unroll
                for (int reg = 0; reg < 4; ++reg) pk[reg] = f2h(acc[reg] + bbv);
                size_t off = (size_t)((idx - 8) * 128 + (n0 >> 5)) * 512
                           + (nt * 2 + (quad >> 1)) * 128 + lq * 8 + (quad & 1) * 4;
                *reinterpret_cast<unsigned long long*>(Vb + off) =
                    __builtin_bit_cast(unsigned long long, pk);
            }
        } else {
            // Q/K: D[h][n] = mfma(wf, xf): h = hb16*16+quad*4+reg, n = n0+nt*16+lq
            unsigned short* dq = (kind ? Kb : Qb);
            const float* bias = (kind ? bk : bq);
            const float scl = kind ? 1.0f : L2E;
            const int hb16 = kind ? (idx - 4) : idx;     // 0..3
            float bb4[4];
            #pragma unroll
            for (int reg = 0; reg < 4; ++reg)
                bb4[reg] = bias[hb16 * 16 + quad * 4 + reg] * scl;
            #pragma unroll
            for (int nt = 0; nt < 2; ++nt) {
                f32x4 acc = (f32x4){0.f, 0.f, 0.f, 0.f};
                #pragma unroll
                for (int ks = 0; ks < 8; ++ks)
                    acc = __builtin_amdgcn_mfma_f32_16x16x32_f16(wf[cur][ks], xf[nt][ks], acc, 0, 0, 0);
                u16x4 pk;
                #pragma unroll
                for (int reg = 0; reg < 4; ++reg) pk[reg] = f2h(acc[reg] + bb4[reg]);
                size_t off = (size_t)((n0 >> 4) + nt) * 1024 + (hb16 >> 1) * 512
                           + ((hb16 & 1) * 2 + (quad >> 1)) * 128 + lq * 8 + (quad & 1) * 4;
                *reinterpret_cast<unsigned long long*>(dq + off) =
                    __builtin_bit_cast(unsigned long long, pk);
            }
        }
    }
}

// ---------------------------------------------------------------------------
// Flash cross-attention v16 = v13 structure, n-split 2x (32 cols/block,
// grid 1024). Block-uniform online softmax via Tsh exchange, deferred
// rescale RTHR=8, double-buffered PT, per-wave roles identical to v13.
// ---------------------------------------------------------------------------
__global__ __launch_bounds__(256, 2) void attn_kernel(
    const float* __restrict__ x1, const float* __restrict__ x2,
    const unsigned short* __restrict__ Qf, const unsigned short* __restrict__ Kf,
    const unsigned short* __restrict__ Vt,
    const float* __restrict__ gamma, float* __restrict__ out)
{
    __shared__ unsigned short PT[2][32 * PTS];   // P^T [n=32][m=128], fp16, dbuf
    __shared__ float Lsh[4][32];
    __shared__ float Tsh[4][32];                 // per-wave tile max exchange

    const int Lb = blockIdx.x;
    const int g = Lb & 7;                        // XCD-locality swizzle
    const int ntile = Lb >> 3;                   // 0..127
    const int d = g >> 2, b = g & 3;
    const int db = d * BAT + b;
    const int s = d, r = 1 - d;
    const int n0 = ntile * 32;

    const int t = threadIdx.x;
    const int lane = t & 63;
    const int w = __builtin_amdgcn_readfirstlane(t >> 6);   // 0..3
    const int quad = lane >> 4, lq = lane & 15;

    const unsigned short* Qb = Qf + (size_t)(s * BAT + b) * (NPIX * HID);
    const unsigned short* Kb = Kf + (size_t)(r * BAT + b) * (NPIX * HID);
    const unsigned short* Vb = Vt + (size_t)(r * BAT + b) * ((size_t)CCH * NPIX);

    // Q fragments, persistent (B-frags), contiguous loads: 2 n-tiles
    h16x8 qf[2][2];
    #pragma unroll
    for (int nt = 0; nt < 2; ++nt)
        #pragma unroll
        for (int ks = 0; ks < 2; ++ks)
            qf[nt][ks] = ldg_fragh(Qb + (size_t)((((n0 >> 4) + nt) * 2) + ks) * 512 + lane * 8);

    f32x4 Oacc[4][2];
    #pragma unroll
    for (int rt = 0; rt < 4; ++rt)
        #pragma unroll
        for (int ct = 0; ct < 2; ++ct)
            Oacc[rt][ct] = (f32x4){0.f, 0.f, 0.f, 0.f};

    float Li[2] = {0.f, 0.f};
    float Mv[2] = {0.f, 0.f};   // BLOCK-uniform running column max

    // K(0) and V(0) fragments (contiguous 1KB/wave loads)
    h16x8 kf[2][2];
    #pragma unroll
    for (int mt = 0; mt < 2; ++mt)
        #pragma unroll
        for (int ks = 0; ks < 2; ++ks)
            kf[mt][ks] = ldg_fragh(Kb + (size_t)((w * 2 + mt) * 2 + ks) * 512 + lane * 8);

    h16x8 vf[4][4];   // vf[ks][rt]
    #pragma unroll
    for (int ks = 0; ks < 4; ++ks)
        #pragma unroll
        for (int rt = 0; rt < 4; ++rt)
            vf[ks][rt] = ldg_fragh(Vb + (size_t)((w * 4 + rt) * 128 + ks) * 512 + lane * 8);

    for (int it = 0; it < 32; ++it) {
        const int buf = it & 1;

        // ---- S phase: Sacc init to -Mv (col n = lq for all 4 C regs) ----
        f32x4 Sacc[2][2];
        #pragma unroll
        for (int mt = 0; mt < 2; ++mt)
            #pragma unroll
            for (int nt = 0; nt < 2; ++nt)
                Sacc[mt][nt] = (f32x4){-Mv[nt], -Mv[nt], -Mv[nt], -Mv[nt]};
        #pragma unroll
        for (int mt = 0; mt < 2; ++mt)
            #pragma unroll
            for (int ks = 0; ks < 2; ++ks)
                #pragma unroll
                for (int nt = 0; nt < 2; ++nt)
                    Sacc[mt][nt] = __builtin_amdgcn_mfma_f32_16x16x32_f16(
                        kf[mt][ks], qf[nt][ks], Sacc[mt][nt], 0, 0, 0);

        // issue K(it+1): covered by the max exchange below
        const int itk = (it < 31) ? it + 1 : 31;
        #pragma unroll
        for (int mt = 0; mt < 2; ++mt)
            #pragma unroll
            for (int ks = 0; ks < 2; ++ks)
                kf[mt][ks] = ldg_fragh(Kb + (size_t)((itk * 8 + w * 2 + mt) * 2 + ks) * 512
                                          + lane * 8);

        // ---- per-wave tile max per column (in-lane 8, then cross-quad) ----
        float trel[2];
        #pragma unroll
        for (int nt = 0; nt < 2; ++nt) {
            float ta = fmaxf(fmaxf(Sacc[0][nt][0], Sacc[0][nt][1]),
                             fmaxf(Sacc[0][nt][2], Sacc[0][nt][3]));
            float tb = fmaxf(fmaxf(Sacc[1][nt][0], Sacc[1][nt][1]),
                             fmaxf(Sacc[1][nt][2], Sacc[1][nt][3]));
            float tm = fmaxf(ta, tb);
            tm = fmaxf(tm, __shfl_xor(tm, 16));
            tm = fmaxf(tm, __shfl_xor(tm, 32));
            trel[nt] = tm;
        }
        if (quad < 2)
            Tsh[w][quad * 16 + lq] = quad ? trel[1] : trel[0];
        __syncthreads();   // barrier 1: tile maxes visible block-wide

        // ---- block max + deferred rescale (identical across all waves) ----
        float bm[2];
        #pragma unroll
        for (int nt = 0; nt < 2; ++nt) {
            int i = nt * 16 + lq;
            bm[nt] = fmaxf(fmaxf(Tsh[0][i], Tsh[1][i]),
                           fmaxf(Tsh[2][i], Tsh[3][i]));
        }
        if (__any((bm[0] > RTHR) || (bm[1] > RTHR))) {
            #pragma unroll
            for (int nt = 0; nt < 2; ++nt) {
                float dlt = fmaxf(bm[nt], 0.f);
                float sc = __builtin_amdgcn_exp2f(-dlt);
                Mv[nt] += dlt;
                Li[nt] *= sc;
                #pragma unroll
                for (int mt = 0; mt < 2; ++mt)
                    #pragma unroll
                    for (int rg = 0; rg < 4; ++rg)
                        Sacc[mt][nt][rg] -= dlt;
                #pragma unroll
                for (int rt = 0; rt < 4; ++rt)
                    #pragma unroll
                    for (int rg = 0; rg < 4; ++rg)
                        Oacc[rt][nt][rg] *= sc;
            }
        }

        // ---- softmax: P = exp2(S - Mv) <= 2^RTHR, fp16, straight to LDS ----
        #pragma unroll
        for (int mt = 0; mt < 2; ++mt)
            #pragma unroll
            for (int nt = 0; nt < 2; ++nt) {
                float p0 = __builtin_amdgcn_exp2f(Sacc[mt][nt][0]);
                float p1 = __builtin_amdgcn_exp2f(Sacc[mt][nt][1]);
                float p2 = __builtin_amdgcn_exp2f(Sacc[mt][nt][2]);
                float p3 = __builtin_amdgcn_exp2f(Sacc[mt][nt][3]);
                Li[nt] += (p0 + p1) + (p2 + p3);
                uint2 pk2;
                pk2.x = pk2h(p0, p1);
                pk2.y = pk2h(p2, p3);
                *reinterpret_cast<uint2*>(
                    &PT[buf][(nt * 16 + lq) * PTS + w * 32 + mt * 16 + quad * 4]) = pk2;
            }
        __syncthreads();   // barrier 2: P tiles ready; K loads complete by now

        // ---- PV: register V + LDS P MFMA over 128 m ----
        #pragma unroll
        for (int ks = 0; ks < 4; ++ks) {
            h16x8 pf[2];
            #pragma unroll
            for (int ct = 0; ct < 2; ++ct)
                pf[ct] = lds_fragh(&PT[buf][(ct * 16 + lq) * PTS + ks * 32 + quad * 8]);
            #pragma unroll
            for (int rt = 0; rt < 4; ++rt)
                #pragma unroll
                for (int ct = 0; ct < 2; ++ct)
                    Oacc[rt][ct] = __builtin_amdgcn_mfma_f32_16x16x32_f16(
                        vf[ks][rt], pf[ct], Oacc[rt][ct], 0, 0, 0);
        }

        // issue V(it+1): S(it+1)+exp2 covers latency
        const int itv = (it < 31) ? it + 1 : 31;
        #pragma unroll
        for (int ks = 0; ks < 4; ++ks)
            #pragma unroll
            for (int rt = 0; rt < 4; ++rt)
                vf[ks][rt] = ldg_fragh(Vb + (size_t)((w * 4 + rt) * 128 + itv * 4 + ks) * 512
                                          + lane * 8);
    }

    // ---- epilogue: merge per-wave L (shared M, plain sum), normalize ----
    #pragma unroll
    for (int nt = 0; nt < 2; ++nt) {
        Li[nt] += __shfl_xor(Li[nt], 16);
        Li[nt] += __shfl_xor(Li[nt], 32);
    }
    if (quad < 2)
        Lsh[w][quad * 16 + lq] = quad ? Li[1] : Li[0];
    __syncthreads();

    float inv[2];
    #pragma unroll
    for (int nt = 0; nt < 2; ++nt) {
        int i = nt * 16 + lq;
        inv[nt] = 1.0f / ((Lsh[0][i] + Lsh[1][i]) + (Lsh[2][i] + Lsh[3][i]));
    }

    const float* xq = d ? x2 : x1;
    const float gm = gamma[0];

    #pragma unroll
    for (int rt = 0; rt < 4; ++rt)
        #pragma unroll
        for (int ct = 0; ct < 2; ++ct)
            #pragma unroll
            for (int rg = 0; rg < 4; ++rg) {
                int c = w * 64 + rt * 16 + quad * 4 + rg;
                int nn = n0 + ct * 16 + lq;
                size_t src = (size_t)(b * CCH + c) * NPIX + nn;
                size_t dst = (size_t)(db * CCH + c) * NPIX + nn;
                out[dst] = xq[src] + gm * Oacc[rt][ct][rg] * inv[ct];
            }
}

// ---------------------------------------------------------------------------
extern "C" void kernel_launch(void* const* d_in, const int* in_sizes, int n_in,
                              void* d_out, int out_size, void* d_ws, size_t ws_size,
                              hipStream_t stream) {
    (void)in_sizes; (void)n_in; (void)out_size; (void)ws_size;
    const float* x1 = (const float*)d_in[0];
    const float* x2 = (const float*)d_in[1];
    const float* Wq = (const float*)d_in[2];
    const float* bq = (const float*)d_in[3];
    const float* Wk = (const float*)d_in[4];
    const float* bk = (const float*)d_in[5];
    const float* Wv = (const float*)d_in[6];
    const float* bv = (const float*)d_in[7];
    const float* gm = (const float*)d_in[8];
    float* out = (float*)d_out;

    // ws (u16 elems): Qf 2.1M | Kf 2.1M | Vt 8.4M | Wg 98304
    unsigned short* ws = (unsigned short*)d_ws;
    unsigned short* Qf = ws;
    unsigned short* Kf = Qf + (size_t)2097152;
    unsigned short* Vt = Kf + (size_t)2097152;
    unsigned short* Wg = Vt + (size_t)8388608;

    wcvt_kernel<<<dim3(48), dim3(256), 0, stream>>>(Wq, Wk, Wv, Wg);
    proj_kernel<<<dim3(1024), dim3(256), 0, stream>>>(
        x1, x2, Wg, bq, bk, bv, Qf, Kf, Vt);
    attn_kernel<<<dim3(1024), dim3(256), 0, stream>>>(
        x1, x2, Qf, Kf, Vt, gm, out);
}

// Round 6
// 192.303 us; speedup vs baseline: 1.1523x; 1.1523x over previous
//
#include <hip/hip_runtime.h>
#include <hip/hip_bf16.h>

#define NPIX 4096
#define CCH  256
#define HID  64
#define BAT  4
#define XSTR 264    // proj LDS row stride (halfs)
#define PTS  136    // attn P-tile row stride (halfs)
#define RTHR 8.0f   // online-softmax defer-rescale threshold (exp2 units)

// Fragment-order tensor layout (round-11):
//   All MFMA operand tensors (Qf, Kf, Vt, Wg) are stored as 16x32 fragment
//   tiles of 512 halfs (1 KB); a wave's fragment load is base + lane*8 halfs
//   -> ONE contiguous 1KB segment per instruction.
//
// Round-17 (this round): attn reverted to the verified v13 structure
//   (97.6us; rounds 14-16 all regressed: reg-cap spill / stall bundle /
//   L2-duplicating n-split). Two independent per-kernel changes:
//   (1) proj: launch_bounds (256,2)->(256,1). proj's live set (xf[2][8] +
//       wf[2][8] = 128 VGPR pinned + ~25 misc) exceeds the 128-VGPR cap the
//       old bound imposed -> scratch spills on the MFMA path. This was the
//       hidden ~85us (total - attn has been ~90-95us constant; wcvt ~2us).
//   (2) attn: raw barriers (lgkmcnt(0) + s_barrier) instead of __syncthreads
//       in the main loop. __syncthreads drains vmcnt(0), forcing K(it+1)/
//       V(it+1) prefetches to complete at the next barrier instead of at
//       first use; raw barriers preserve LDS visibility (PT/Tsh/pf are all
//       lgkm-counted DS ops) while global loads span barriers (T4 mechanism,
//       compiler inserts counted vmcnt(N) at first use).

using f32x4 = __attribute__((ext_vector_type(4))) float;
using h16x8 = __attribute__((ext_vector_type(8))) _Float16;
using u16x4 = __attribute__((ext_vector_type(4))) unsigned short;

#define L2E 1.44269504088896340736f

// LDS-only barrier: guarantees this wave's DS ops (LDS writes/reads,
// shuffles) are complete before the barrier, but leaves global-memory
// loads (vmcnt) in flight across it. Consumers' own DS reads after the
// barrier get compiler-inserted lgkm waits as usual.
#define LDS_BARRIER() do {                                    \
    __builtin_amdgcn_sched_barrier(0);                        \
    asm volatile("s_waitcnt lgkmcnt(0)" ::: "memory");        \
    __builtin_amdgcn_s_barrier();                             \
    __builtin_amdgcn_sched_barrier(0);                        \
} while (0)

__device__ __forceinline__ unsigned short f2h(float f) {
    _Float16 h = (_Float16)f;
    return __builtin_bit_cast(unsigned short, h);
}
__device__ __forceinline__ h16x8 ldg_fragh(const unsigned short* p) {
    uint4 v = *reinterpret_cast<const uint4*>(p);
    return __builtin_bit_cast(h16x8, v);
}
__device__ __forceinline__ h16x8 lds_fragh(const unsigned short* p) {
    return *reinterpret_cast<const h16x8*>(p);
}
__device__ __forceinline__ unsigned int pk2h(float a, float b) {
    auto t = __builtin_amdgcn_cvt_pkrtz(a, b);   // <2 x half>, RTZ
    return __builtin_bit_cast(unsigned int, t);
}
__device__ __forceinline__ float sel4(float a0, float a1, float a2, float a3, int q) {
    float x = (q & 1) ? a1 : a0;
    float y = (q & 1) ? a3 : a2;
    return (q & 2) ? y : x;
}

// ---------------------------------------------------------------------------
// W conversion -> frag-order Wg [384 rows][256 k] fp16: 24 row-tiles x 8
// k-tiles = 192 tiles x 512 halfs. Rows 0-63 Wq (x log2e), 64-127 Wk, rest Wv.
// ---------------------------------------------------------------------------
__global__ __launch_bounds__(256, 1) void wcvt_kernel(
    const float* __restrict__ Wq, const float* __restrict__ Wk,
    const float* __restrict__ Wv, unsigned short* __restrict__ Wg)
{
    int tid = blockIdx.x * 256 + threadIdx.x;       // 0..12287
    int tile = tid >> 6, lane = tid & 63;
    int r = (tile >> 3) * 16 + (lane & 15);
    int c = (tile & 7) * 32 + (lane >> 4) * 8;
    const float* src; float sc;
    if (r < 64)       { src = Wq + r * CCH + c;        sc = L2E; }
    else if (r < 128) { src = Wk + (r - 64) * CCH + c; sc = 1.0f; }
    else              { src = Wv + (r - 128) * CCH + c; sc = 1.0f; }
    float4 a = *reinterpret_cast<const float4*>(src);
    float4 b4 = *reinterpret_cast<const float4*>(src + 4);
    uint4 out;
    out.x = pk2h(a.x * sc, a.y * sc);
    out.y = pk2h(a.z * sc, a.w * sc);
    out.z = pk2h(b4.x * sc, b4.y * sc);
    out.w = pk2h(b4.z * sc, b4.w * sc);
    *reinterpret_cast<uint4*>(Wg + tile * 512 + lane * 8) = out;
}

// ---------------------------------------------------------------------------
// fp16 MFMA projection v11 + round-17 fix: launch_bounds (256,1).
// Live fragment state xf[2][8]+wf[2][8] = 128 VGPR alone; the old (256,2)
// 128-VGPR cap forced scratch spills on the MFMA critical path.
// ---------------------------------------------------------------------------
__global__ __launch_bounds__(256, 1) void proj_kernel(
    const float* __restrict__ x1, const float* __restrict__ x2,
    const unsigned short* __restrict__ Wg,
    const float* __restrict__ bq, const float* __restrict__ bk,
    const float* __restrict__ bv,
    unsigned short* __restrict__ Qf, unsigned short* __restrict__ Kf,
    unsigned short* __restrict__ Vt)
{
    __shared__ unsigned short xs[32][XSTR];

    const int Lb = blockIdx.x;
    const int sb = Lb & 7;              // XCD-locality swizzle
    const int tile = Lb >> 3;
    const int s = sb >> 2, b = sb & 3;
    const float* x = s ? x2 : x1;
    const int n0 = tile * 32;
    const int t = threadIdx.x;
    const int lane = t & 63;
    const int w = __builtin_amdgcn_readfirstlane(t >> 6);
    const int quad = lane >> 4, lq = lane & 15;

    // stage x^T fp16 into LDS
    {
        const int n = t & 31;
        const int g = t >> 5;
        const float* xb = x + (size_t)(b * CCH) * NPIX + n0;
        #pragma unroll
        for (int i = 0; i < 8; ++i) {
            int c0 = g * 4 + i * 32;
            u16x4 hv;
            #pragma unroll
            for (int j = 0; j < 4; ++j)
                hv[j] = f2h(xb[(size_t)(c0 + j) * NPIX + n]);
            *reinterpret_cast<u16x4*>(&xs[n][c0]) = hv;
        }
    }
    __syncthreads();

    // hoist x fragments (both ntiles, full K=256)
    h16x8 xf[2][8];
    #pragma unroll
    for (int nt = 0; nt < 2; ++nt)
        #pragma unroll
        for (int ks = 0; ks < 8; ++ks)
            xf[nt][ks] = lds_fragh(&xs[nt * 16 + lq][ks * 32 + quad * 8]);

    unsigned short* Qb = Qf + (size_t)(s * BAT + b) * (NPIX * HID);
    unsigned short* Kb = Kf + (size_t)(s * BAT + b) * (NPIX * HID);
    unsigned short* Vb = Vt + (size_t)(s * BAT + b) * ((size_t)CCH * NPIX);

    // W fragment double-buffer, frag-order contiguous loads
    h16x8 wf[2][8];
    {
        const unsigned short* wp = Wg + (size_t)(w * 6 * 8) * 512 + lane * 8;
        #pragma unroll
        for (int ks = 0; ks < 8; ++ks) wf[0][ks] = ldg_fragh(wp + ks * 512);
    }

    #pragma unroll
    for (int hloop = 0; hloop < 6; ++hloop) {
        const int cur = hloop & 1;
        const int idx = w * 6 + hloop;                  // wave-uniform, 0..23
        const int kind = idx < 4 ? 0 : (idx < 8 ? 1 : 2);

        if (hloop < 5) {
            const unsigned short* wp = Wg + (size_t)((idx + 1) * 8) * 512 + lane * 8;
            #pragma unroll
            for (int ks = 0; ks < 8; ++ks) wf[cur ^ 1][ks] = ldg_fragh(wp + ks * 512);
        }

        if (kind == 2) {
            // V: D[n][c] = mfma(xf, wf): m = n0+nt*16+quad*4+reg, c = cbase+lq
            const int cbase = (idx - 8) * 16;
            const float bbv = bv[cbase + lq];
            #pragma unroll
            for (int nt = 0; nt < 2; ++nt) {
                f32x4 acc = (f32x4){0.f, 0.f, 0.f, 0.f};
                #pragma unroll
                for (int ks = 0; ks < 8; ++ks)
                    acc = __builtin_amdgcn_mfma_f32_16x16x32_f16(xf[nt][ks], wf[cur][ks], acc, 0, 0, 0);
                u16x4 pk;
                #pragma unroll
                for (int reg = 0; reg < 4; ++reg) pk[reg] = f2h(acc[reg] + bbv);
                size_t off = (size_t)((idx - 8) * 128 + (n0 >> 5)) * 512
                           + (nt * 2 + (quad >> 1)) * 128 + lq * 8 + (quad & 1) * 4;
                *reinterpret_cast<unsigned long long*>(Vb + off) =
                    __builtin_bit_cast(unsigned long long, pk);
            }
        } else {
            // Q/K: D[h][n] = mfma(wf, xf): h = hb16*16+quad*4+reg, n = n0+nt*16+lq
            unsigned short* dq = (kind ? Kb : Qb);
            const float* bias = (kind ? bk : bq);
            const float scl = kind ? 1.0f : L2E;
            const int hb16 = kind ? (idx - 4) : idx;     // 0..3
            float bb4[4];
            #pragma unroll
            for (int reg = 0; reg < 4; ++reg)
                bb4[reg] = bias[hb16 * 16 + quad * 4 + reg] * scl;
            #pragma unroll
            for (int nt = 0; nt < 2; ++nt) {
                f32x4 acc = (f32x4){0.f, 0.f, 0.f, 0.f};
                #pragma unroll
                for (int ks = 0; ks < 8; ++ks)
                    acc = __builtin_amdgcn_mfma_f32_16x16x32_f16(wf[cur][ks], xf[nt][ks], acc, 0, 0, 0);
                u16x4 pk;
                #pragma unroll
                for (int reg = 0; reg < 4; ++reg) pk[reg] = f2h(acc[reg] + bb4[reg]);
                size_t off = (size_t)((n0 >> 4) + nt) * 1024 + (hb16 >> 1) * 512
                           + ((hb16 & 1) * 2 + (quad >> 1)) * 128 + lq * 8 + (quad & 1) * 4;
                *reinterpret_cast<unsigned long long*>(dq + off) =
                    __builtin_bit_cast(unsigned long long, pk);
            }
        }
    }
}

// ---------------------------------------------------------------------------
// Flash cross-attention v17 = v13 (verified 97.6us) with raw LDS barriers:
// global K/V prefetches stay in flight across barriers; all LDS traffic
// (PT writes, Tsh/Lsh exchange, pf reads, shuffles) is lgkm-counted and
// forced complete before each barrier, so the v13 race-freedom argument
// carries over unchanged.
// ---------------------------------------------------------------------------
__global__ __launch_bounds__(256, 2) void attn_kernel(
    const float* __restrict__ x1, const float* __restrict__ x2,
    const unsigned short* __restrict__ Qf, const unsigned short* __restrict__ Kf,
    const unsigned short* __restrict__ Vt,
    const float* __restrict__ gamma, float* __restrict__ out)
{
    __shared__ unsigned short PT[2][64 * PTS];   // P^T [n=64][m=128], fp16, dbuf
    __shared__ float Lsh[4][64];
    __shared__ float Tsh[4][64];                 // per-wave tile max exchange

    const int Lb = blockIdx.x;
    const int g = Lb & 7;                        // XCD-locality swizzle
    const int ntile = Lb >> 3;
    const int d = g >> 2, b = g & 3;
    const int db = d * BAT + b;
    const int s = d, r = 1 - d;
    const int n0 = ntile * 64;

    const int t = threadIdx.x;
    const int lane = t & 63;
    const int w = __builtin_amdgcn_readfirstlane(t >> 6);
    const int quad = lane >> 4, lq = lane & 15;

    const unsigned short* Qb = Qf + (size_t)(s * BAT + b) * (NPIX * HID);
    const unsigned short* Kb = Kf + (size_t)(r * BAT + b) * (NPIX * HID);
    const unsigned short* Vb = Vt + (size_t)(r * BAT + b) * ((size_t)CCH * NPIX);

    // Q fragments, persistent (B-frags), contiguous loads
    h16x8 qf[4][2];
    #pragma unroll
    for (int nt = 0; nt < 4; ++nt)
        #pragma unroll
        for (int ks = 0; ks < 2; ++ks)
            qf[nt][ks] = ldg_fragh(Qb + (size_t)((((n0 >> 4) + nt) * 2) + ks) * 512 + lane * 8);

    f32x4 Oacc[4][4];
    #pragma unroll
    for (int rt = 0; rt < 4; ++rt)
        #pragma unroll
        for (int ct = 0; ct < 4; ++ct)
            Oacc[rt][ct] = (f32x4){0.f, 0.f, 0.f, 0.f};

    float Li[4] = {0.f, 0.f, 0.f, 0.f};
    float Mv[4] = {0.f, 0.f, 0.f, 0.f};   // BLOCK-uniform running column max

    // K(0) and V(0) fragments (contiguous 1KB/wave loads)
    h16x8 kf[2][2];
    #pragma unroll
    for (int mt = 0; mt < 2; ++mt)
        #pragma unroll
        for (int ks = 0; ks < 2; ++ks)
            kf[mt][ks] = ldg_fragh(Kb + (size_t)((w * 2 + mt) * 2 + ks) * 512 + lane * 8);

    h16x8 vf[4][4];   // vf[ks][rt]
    #pragma unroll
    for (int ks = 0; ks < 4; ++ks)
        #pragma unroll
        for (int rt = 0; rt < 4; ++rt)
            vf[ks][rt] = ldg_fragh(Vb + (size_t)((w * 4 + rt) * 128 + ks) * 512 + lane * 8);

    for (int it = 0; it < 32; ++it) {
        const int buf = it & 1;

        // ---- S phase: Sacc init to -Mv (col n = lq for all 4 C regs) ----
        f32x4 Sacc[2][4];
        #pragma unroll
        for (int mt = 0; mt < 2; ++mt)
            #pragma unroll
            for (int nt = 0; nt < 4; ++nt)
                Sacc[mt][nt] = (f32x4){-Mv[nt], -Mv[nt], -Mv[nt], -Mv[nt]};
        #pragma unroll
        for (int mt = 0; mt < 2; ++mt)
            #pragma unroll
            for (int ks = 0; ks < 2; ++ks)
                #pragma unroll
                for (int nt = 0; nt < 4; ++nt)
                    Sacc[mt][nt] = __builtin_amdgcn_mfma_f32_16x16x32_f16(
                        kf[mt][ks], qf[nt][ks], Sacc[mt][nt], 0, 0, 0);

        // issue K(it+1): now genuinely spans the barriers (no vmcnt drain)
        const int itk = (it < 31) ? it + 1 : 31;
        #pragma unroll
        for (int mt = 0; mt < 2; ++mt)
            #pragma unroll
            for (int ks = 0; ks < 2; ++ks)
                kf[mt][ks] = ldg_fragh(Kb + (size_t)((itk * 8 + w * 2 + mt) * 2 + ks) * 512
                                          + lane * 8);

        // ---- per-wave tile max per column (in-lane 8, then cross-quad) ----
        float trel[4];
        #pragma unroll
        for (int nt = 0; nt < 4; ++nt) {
            float ta = fmaxf(fmaxf(Sacc[0][nt][0], Sacc[0][nt][1]),
                             fmaxf(Sacc[0][nt][2], Sacc[0][nt][3]));
            float tb = fmaxf(fmaxf(Sacc[1][nt][0], Sacc[1][nt][1]),
                             fmaxf(Sacc[1][nt][2], Sacc[1][nt][3]));
            float tm = fmaxf(ta, tb);
            tm = fmaxf(tm, __shfl_xor(tm, 16));
            tm = fmaxf(tm, __shfl_xor(tm, 32));
            trel[nt] = tm;
        }
        Tsh[w][quad * 16 + lq] = sel4(trel[0], trel[1], trel[2], trel[3], quad);
        LDS_BARRIER();     // barrier 1: tile maxes visible block-wide

        // ---- block max + deferred rescale (identical across all waves) ----
        float bm[4];
        #pragma unroll
        for (int nt = 0; nt < 4; ++nt) {
            int i = nt * 16 + lq;
            bm[nt] = fmaxf(fmaxf(Tsh[0][i], Tsh[1][i]),
                           fmaxf(Tsh[2][i], Tsh[3][i]));
        }
        if (__any((bm[0] > RTHR) || (bm[1] > RTHR) ||
                  (bm[2] > RTHR) || (bm[3] > RTHR))) {
            #pragma unroll
            for (int nt = 0; nt < 4; ++nt) {
                float dlt = fmaxf(bm[nt], 0.f);
                float sc = __builtin_amdgcn_exp2f(-dlt);
                Mv[nt] += dlt;
                Li[nt] *= sc;
                #pragma unroll
                for (int mt = 0; mt < 2; ++mt)
                    #pragma unroll
                    for (int rg = 0; rg < 4; ++rg)
                        Sacc[mt][nt][rg] -= dlt;
                #pragma unroll
                for (int rt = 0; rt < 4; ++rt)
                    #pragma unroll
                    for (int rg = 0; rg < 4; ++rg)
                        Oacc[rt][nt][rg] *= sc;
            }
        }

        // ---- softmax: P = exp2(S - Mv) <= 2^RTHR, fp16, straight to LDS ----
        #pragma unroll
        for (int mt = 0; mt < 2; ++mt)
            #pragma unroll
            for (int nt = 0; nt < 4; ++nt) {
                float p0 = __builtin_amdgcn_exp2f(Sacc[mt][nt][0]);
                float p1 = __builtin_amdgcn_exp2f(Sacc[mt][nt][1]);
                float p2 = __builtin_amdgcn_exp2f(Sacc[mt][nt][2]);
                float p3 = __builtin_amdgcn_exp2f(Sacc[mt][nt][3]);
                Li[nt] += (p0 + p1) + (p2 + p3);
                uint2 pk2;
                pk2.x = pk2h(p0, p1);
                pk2.y = pk2h(p2, p3);
                *reinterpret_cast<uint2*>(
                    &PT[buf][(nt * 16 + lq) * PTS + w * 32 + mt * 16 + quad * 4]) = pk2;
            }
        LDS_BARRIER();     // barrier 2: P tiles ready (K loads still in flight)

        // ---- PV: pure register+LDS MFMA over 128 m ----
        #pragma unroll
        for (int ks = 0; ks < 4; ++ks) {
            h16x8 pf[4];
            #pragma unroll
            for (int ct = 0; ct < 4; ++ct)
                pf[ct] = lds_fragh(&PT[buf][(ct * 16 + lq) * PTS + ks * 32 + quad * 8]);
            #pragma unroll
            for (int rt = 0; rt < 4; ++rt)
                #pragma unroll
                for (int ct = 0; ct < 4; ++ct)
                    Oacc[rt][ct] = __builtin_amdgcn_mfma_f32_16x16x32_f16(
                        vf[ks][rt], pf[ct], Oacc[rt][ct], 0, 0, 0);
        }

        // issue V(it+1): spans next iteration's barriers
        const int itv = (it < 31) ? it + 1 : 31;
        #pragma unroll
        for (int ks = 0; ks < 4; ++ks)
            #pragma unroll
            for (int rt = 0; rt < 4; ++rt)
                vf[ks][rt] = ldg_fragh(Vb + (size_t)((w * 4 + rt) * 128 + itv * 4 + ks) * 512
                                          + lane * 8);
    }

    // ---- epilogue: merge per-wave L (shared M, plain sum), normalize ----
    #pragma unroll
    for (int nt = 0; nt < 4; ++nt) {
        Li[nt] += __shfl_xor(Li[nt], 16);
        Li[nt] += __shfl_xor(Li[nt], 32);
    }
    Lsh[w][quad * 16 + lq] = sel4(Li[0], Li[1], Li[2], Li[3], quad);
    __syncthreads();

    float inv[4];
    #pragma unroll
    for (int nt = 0; nt < 4; ++nt) {
        int i = nt * 16 + lq;
        inv[nt] = 1.0f / ((Lsh[0][i] + Lsh[1][i]) + (Lsh[2][i] + Lsh[3][i]));
    }

    const float* xq = d ? x2 : x1;
    const float gm = gamma[0];

    #pragma unroll
    for (int rt = 0; rt < 4; ++rt)
        #pragma unroll
        for (int ct = 0; ct < 4; ++ct)
            #pragma unroll
            for (int rg = 0; rg < 4; ++rg) {
                int c = w * 64 + rt * 16 + quad * 4 + rg;
                int nn = n0 + ct * 16 + lq;
                size_t src = (size_t)(b * CCH + c) * NPIX + nn;
                size_t dst = (size_t)(db * CCH + c) * NPIX + nn;
                out[dst] = xq[src] + gm * Oacc[rt][ct][rg] * inv[ct];
            }
}

// ---------------------------------------------------------------------------
extern "C" void kernel_launch(void* const* d_in, const int* in_sizes, int n_in,
                              void* d_out, int out_size, void* d_ws, size_t ws_size,
                              hipStream_t stream) {
    (void)in_sizes; (void)n_in; (void)out_size; (void)ws_size;
    const float* x1 = (const float*)d_in[0];
    const float* x2 = (const float*)d_in[1];
    const float* Wq = (const float*)d_in[2];
    const float* bq = (const float*)d_in[3];
    const float* Wk = (const float*)d_in[4];
    const float* bk = (const float*)d_in[5];
    const float* Wv = (const float*)d_in[6];
    const float* bv = (const float*)d_in[7];
    const float* gm = (const float*)d_in[8];
    float* out = (float*)d_out;

    // ws (u16 elems): Qf 2.1M | Kf 2.1M | Vt 8.4M | Wg 98304
    unsigned short* ws = (unsigned short*)d_ws;
    unsigned short* Qf = ws;
    unsigned short* Kf = Qf + (size_t)2097152;
    unsigned short* Vt = Kf + (size_t)2097152;
    unsigned short* Wg = Vt + (size_t)8388608;

    wcvt_kernel<<<dim3(48), dim3(256), 0, stream>>>(Wq, Wk, Wv, Wg);
    proj_kernel<<<dim3(1024), dim3(256), 0, stream>>>(
        x1, x2, Wg, bq, bk, bv, Qf, Kf, Vt);
    attn_kernel<<<dim3(512), dim3(256), 0, stream>>>(
        x1, x2, Qf, Kf, Vt, gm, out);
}